// Round 9
// baseline (219.501 us; speedup 1.0000x reference)
//
#include <hip/hip_runtime.h>

#define M_DIM 8192
#define N_DIM 2048
#define K_DIM 2048

#define BM 256
#define BN 256
#define BK 64
#define NT (K_DIM / BK)

#define AS1 __attribute__((address_space(1)))
#define AS3 __attribute__((address_space(3)))

typedef float f32x4 __attribute__((ext_vector_type(4)));
typedef short s16x8 __attribute__((ext_vector_type(8)));

__device__ __forceinline__ unsigned short f2bf(float f) {
  unsigned int u = __float_as_uint(f);
  u += 0x7FFFu + ((u >> 16) & 1u);   // round-to-nearest-even
  return (unsigned short)(u >> 16);
}

// ---------------------------------------------------------------------------
// Kernel 1 (merged): blocks [0, M_DIM) do per-token int8 fake-quant of x;
// blocks [M_DIM, ...) do grouped int4 dequant of W.
// ---------------------------------------------------------------------------
__global__ __launch_bounds__(256) void prep_kernel(
    const float* __restrict__ x, const int* __restrict__ w,
    const float* __restrict__ ws, const float* __restrict__ wz,
    unsigned short* __restrict__ A, unsigned short* __restrict__ W) {
  const int tid = threadIdx.x;
  if (blockIdx.x < M_DIM) {
    const int t = blockIdx.x;
    const float4* r4 = (const float4*)(x + (size_t)t * K_DIM);
    float4 v0 = r4[tid];
    float4 v1 = r4[tid + 256];

    float mn = fminf(fminf(fminf(v0.x, v0.y), fminf(v0.z, v0.w)),
                     fminf(fminf(v1.x, v1.y), fminf(v1.z, v1.w)));
    float mx = fmaxf(fmaxf(fmaxf(v0.x, v0.y), fmaxf(v0.z, v0.w)),
                     fmaxf(fmaxf(v1.x, v1.y), fmaxf(v1.z, v1.w)));
#pragma unroll
    for (int off = 32; off > 0; off >>= 1) {
      mn = fminf(mn, __shfl_xor(mn, off));
      mx = fmaxf(mx, __shfl_xor(mx, off));
    }
    __shared__ float smn[4], smx[4];
    if ((tid & 63) == 0) { smn[tid >> 6] = mn; smx[tid >> 6] = mx; }
    __syncthreads();
    mn = fminf(fminf(smn[0], smn[1]), fminf(smn[2], smn[3]));
    mx = fmaxf(fmaxf(smx[0], smx[1]), fmaxf(smx[2], smx[3]));
    mn = fminf(mn, 0.0f);
    mx = fmaxf(mx, 0.0f);

    float scale = (mx - mn) / 255.0f;                 // (QMAX-QMIN)=255
    scale = fmaxf(scale, 1.1920928955078125e-07f);    // f32 eps = 2^-23
    const float inv = 1.0f / scale;                   // one IEEE div per token
    float zp = -128.0f - rintf(mn * inv);
    zp = fminf(fmaxf(zp, -128.0f), 127.0f);

    ushort4* Ao = (ushort4*)(A + (size_t)t * K_DIM);
    {
      float q; ushort4 r;
      q = rintf(v0.x * inv) + zp; q = fminf(fmaxf(q, -128.f), 127.f); r.x = f2bf((q - zp) * scale);
      q = rintf(v0.y * inv) + zp; q = fminf(fmaxf(q, -128.f), 127.f); r.y = f2bf((q - zp) * scale);
      q = rintf(v0.z * inv) + zp; q = fminf(fmaxf(q, -128.f), 127.f); r.z = f2bf((q - zp) * scale);
      q = rintf(v0.w * inv) + zp; q = fminf(fmaxf(q, -128.f), 127.f); r.w = f2bf((q - zp) * scale);
      Ao[tid] = r;
    }
    {
      float q; ushort4 r;
      q = rintf(v1.x * inv) + zp; q = fminf(fmaxf(q, -128.f), 127.f); r.x = f2bf((q - zp) * scale);
      q = rintf(v1.y * inv) + zp; q = fminf(fmaxf(q, -128.f), 127.f); r.y = f2bf((q - zp) * scale);
      q = rintf(v1.z * inv) + zp; q = fminf(fmaxf(q, -128.f), 127.f); r.z = f2bf((q - zp) * scale);
      q = rintf(v1.w * inv) + zp; q = fminf(fmaxf(q, -128.f), 127.f); r.w = f2bf((q - zp) * scale);
      Ao[tid + 256] = r;
    }
  } else {
    const int idx = (blockIdx.x - M_DIM) * 256 + tid;  // one 8-elem chunk
    const int o  = idx >> 8;                           // 2048/8 = 256 chunks/row
    const int ii = (idx & 255) * 8;
    const int g  = ii >> 5;                            // GROUPSIZE=32
    const float s = ws[o * 64 + g];
    const float z = wz[o * 64 + g];
    const int4* wp = (const int4*)(w + (size_t)o * K_DIM + ii);
    int4 a = wp[0], b = wp[1];
    ushort4 r0, r1;
    r0.x = f2bf(((float)a.x - z) * s);
    r0.y = f2bf(((float)a.y - z) * s);
    r0.z = f2bf(((float)a.z - z) * s);
    r0.w = f2bf(((float)a.w - z) * s);
    r1.x = f2bf(((float)b.x - z) * s);
    r1.y = f2bf(((float)b.y - z) * s);
    r1.z = f2bf(((float)b.z - z) * s);
    r1.w = f2bf(((float)b.w - z) * s);
    ushort4* Wo = (ushort4*)(W + (size_t)o * K_DIM + ii);
    Wo[0] = r0;
    Wo[1] = r1;
  }
}

// ---------------------------------------------------------------------------
// Kernel 2: C[M][N] = A[M][K] * B[N][K]^T, bf16 in, f32 out.
// r6 skeleton (2 barriers/tile, hand-gated) with B REMOVED FROM LDS:
// B fragments load straight from global (L2/L3-hot via XCD swizzle) with
// inline-asm global_load_dwordx4. LDS traffic/tile/CU: reads 192->128
// (~1540 cyc), writes 64->32 KB (~256 cyc) => ~1800 < 2480 MFMA => slack.
//
// B regs: TWO arrays (bU,bV) with parity role-swap. At iter t: BP holds
// n0(t) (loaded during iter t-1); BJ gets n1(t) at sec1; after Q11 (last
// reader of n1) the SAME array receives n0(t+1). WAR on regs is safe:
// MFMA reads operands at issue; anti-dep keeps program order.
//
// A staging split by usage: rounds {0,2} (af0 rows of both wave-groups)
// staged at sec1, published BAR_A, read-ahead at sec2; rounds {1,3} (af1)
// staged at sec2, published BAR_B, read at sec1(t+1).
//
// Per-wave in-order vm ledger (gates in parens; pf = t+1 < NT):
//   enter 4 [n0(t)] -> +4 n1 +2 stg02 = 10 -> (6): n0 ready -> Q00
//   -> (2): n1 ready -> Q01 -> (0): stg02 landed -> BAR_A
//   -> +2 stg13 -> Q11 -> +4 n0(t+1) = 6 -> Q10 -> (4): stg13 landed
//   -> BAR_B -> exit 4.  All tail iters fall back to full drains.
// Per-wave lgkm ledger: enter 8 [af0] -> +4 af1k0 = 12 -> (4): af0 ready
//   -> +4 af1k1 = 8 -> Q00,Q01 -> (0): af1 ready -> +8 af0' -> Q11,Q10
//   -> exit 8.  Peak 12 <= 15 (4-bit limit).
// Every vm gate trails its newest retired load by >=620 cyc (one MFMA
// quadrant); boundary vmcnt(4) keeps n0(t+1) in flight across BAR_B.
// LDS deadness: each staged round's last reader retired >=1 barrier
// before the stage issues (af0(t-1) at GATE(4)/sec1(t-1) < BAR_B(t-1);
// af1(t-1) at GATE(0)/sec2(t-1) < BAR_B(t-1)).
// B bits pass through unchanged; MFMA quadrant order (0,0)(0,1)(1,1)(1,0)
// and per-acc kk order preserved -> bit-identical numerics.
// ---------------------------------------------------------------------------

#define SFENCE() __builtin_amdgcn_sched_barrier(0)

#define DSR(dst, addr, IMM)                                                  \
  asm volatile("ds_read_b128 %0, %1 offset:%2"                               \
               : "=v"(dst) : "v"(addr), "i"(IMM))

#define GLB(dst, ptr, IMM)                                                   \
  asm volatile("global_load_dwordx4 %0, %1, off offset:%2"                   \
               : "=v"(dst) : "v"(ptr), "i"(IMM))

#define LGKM_GATE(N)                                                         \
  do {                                                                       \
    asm volatile("s_waitcnt lgkmcnt(%0)" :: "i"(N) : "memory");              \
    SFENCE();                                                                \
  } while (0)

#define VM_GATE(N)                                                           \
  do {                                                                       \
    asm volatile("s_waitcnt vmcnt(%0)" :: "i"(N) : "memory");                \
    SFENCE();                                                                \
  } while (0)

#define RD_A(dst, MH, PLIT)                                                  \
  do {                                                                       \
    _Pragma("unroll") for (int i = 0; i < 4; ++i) {                          \
      _Pragma("unroll") for (int kk = 0; kk < 2; ++kk) {                     \
        DSR(dst[i][kk], a_addr[kk],                                          \
            (PLIT) * 32768 + ((MH) * 4 + i) * 2048);                         \
      }                                                                      \
    }                                                                        \
  } while (0)

#define RD_A_K(dst, MH, KK, PLIT)                                            \
  do {                                                                       \
    _Pragma("unroll") for (int i = 0; i < 4; ++i) {                          \
      DSR(dst[i][KK], a_addr[KK],                                            \
          (PLIT) * 32768 + ((MH) * 4 + i) * 2048);                           \
    }                                                                        \
  } while (0)

#define MFMA_Q(afX, bfX, MH, NH)                                             \
  do {                                                                       \
    __builtin_amdgcn_s_setprio(1);                                           \
    _Pragma("unroll") for (int kk = 0; kk < 2; ++kk) {                       \
      _Pragma("unroll") for (int i = 0; i < 4; ++i) {                        \
        _Pragma("unroll") for (int j = 0; j < 2; ++j) {                      \
          acc[(MH) * 4 + i][(NH) * 2 + j] =                                  \
              __builtin_amdgcn_mfma_f32_16x16x32_bf16(                       \
                  afX[i][kk], bfX[j][kk],                                    \
                  acc[(MH) * 4 + i][(NH) * 2 + j], 0, 0, 0);                 \
        }                                                                    \
      }                                                                      \
    }                                                                        \
    __builtin_amdgcn_s_setprio(0);                                           \
  } while (0)

// Stage ONE 64-row round R (rows trow + R*64) of the A tile: 1 glds instr,
// 512 threads x 16 B = 8 KB.
#define STAGE_R(KN, DSTP, R)                                                 \
  __builtin_amdgcn_global_load_lds(                                          \
      (const AS1 void*)(ag + (size_t)(R) * 64 * K_DIM + (KN)),               \
      (AS3 void*)(&As[(DSTP) * (BM * BK) + (R) * 4096 + tid * 8]), 16, 0, 0)

// One K-tile. PLIT = compile-time parity literal (0/1). BP = array holding
// n0(t); BJ = array receiving n1(t), then n0(t+1) after Q11.
#define ITER(KT, PLIT, BP, BJ)                                               \
  {                                                                          \
    const int k1 = ((KT) + 1) * BK;                                          \
    const bool pf = (KT) + 1 < NT;                                           \
    /* -- sec1 -- */                                                         \
    GLB(BJ[0][0], bg2, 0);   GLB(BJ[0][1], bg2, 64);   /* n1(t) */           \
    GLB(BJ[1][0], bg3, 0);   GLB(BJ[1][1], bg3, 64);                         \
    if (pf) { STAGE_R(k1, (PLIT) ^ 1, 0); STAGE_R(k1, (PLIT) ^ 1, 2); }      \
    RD_A_K(af1, 1, 0, PLIT);        /* lgkm -> 12 */                         \
    LGKM_GATE(4);                   /* af0 ready */                          \
    RD_A_K(af1, 1, 1, PLIT);        /* lgkm -> 8 */                          \
    SFENCE();                                                                \
    if (pf) { VM_GATE(6); } else { VM_GATE(4); }   /* n0(t) ready */         \
    MFMA_Q(af0, BP, 0, 0);          /* Q00 */                                \
    SFENCE();                                                                \
    if (pf) { VM_GATE(2); } else { VM_GATE(0); }   /* n1(t) ready */         \
    MFMA_Q(af0, BJ, 0, 1);          /* Q01 */                                \
    SFENCE();                                                                \
    VM_GATE(0);                     /* stage {0,2}(t+1) landed */            \
    __builtin_amdgcn_s_barrier();   /* BAR_A: rounds {0,2} published */      \
    SFENCE();                                                                \
    /* -- sec2 -- */                                                         \
    LGKM_GATE(0);                   /* af1 ready */                          \
    if (pf) {                                                                \
      RD_A(af0, 0, (PLIT) ^ 1);     /* af0(t+1) x8, under Q11/Q10 */         \
      STAGE_R(k1, (PLIT) ^ 1, 1); STAGE_R(k1, (PLIT) ^ 1, 3);                \
    }                                                                        \
    SFENCE();                                                                \
    MFMA_Q(af1, BJ, 1, 1);          /* Q11: last reader of n1(t) */          \
    SFENCE();                                                                \
    if (pf) {                                                                \
      GLB(BJ[0][0], bg0, 128); GLB(BJ[0][1], bg0, 192);  /* n0(t+1)->BJ */   \
      GLB(BJ[1][0], bg1, 128); GLB(BJ[1][1], bg1, 192);                      \
    }                                                                        \
    SFENCE();                                                                \
    MFMA_Q(af1, BP, 1, 0);          /* Q10 */                                \
    SFENCE();                                                                \
    if (pf) { VM_GATE(4); } else { VM_GATE(0); }   /* stage {1,3} landed */  \
    __builtin_amdgcn_s_barrier();   /* BAR_B: rounds {1,3} published */      \
    SFENCE();                                                                \
    bg0 += 64; bg1 += 64; bg2 += 64; bg3 += 64;  /* advance one K-tile */    \
  }

__global__ __launch_bounds__(512, 2) void gemm_kernel(
    const unsigned short* __restrict__ A,
    const unsigned short* __restrict__ B,
    float* __restrict__ C) {
  __shared__ unsigned short As[2 * BM * BK];  // 64 KB, double-buffered (A only)

  const int tid = threadIdx.x;
  // XCD swizzle: linear dispatch id = by*8+bx, id%8 ~ XCD. Each XCD gets a
  // contiguous 4-slab M range x full N (bijective, nwg=256 = 8*32) -> its
  // 4 MiB A-slab stays in its L2; B panels (8 MB) live in L2+L3.
  const int id  = blockIdx.y * 8 + blockIdx.x;
  const int nid = (id & 7) * 32 + (id >> 3);
  const int bm  = (nid >> 3) * BM;
  const int bn  = (nid & 7) * BN;

  const int lane  = tid & 63;
  const int wv    = tid >> 6;
  const int waveM = (wv >> 2) * 128;   // 2 M-waves
  const int waveN = (wv & 3) * 64;     // 4 N-waves
  const int quad  = lane >> 4;
  const int l16   = lane & 15;

  // --- A staging: row = trow + round*64, chunk (phys) = (tid&7)^(trow&7).
  const int trow = tid >> 3;                    // 0..63
  const int phys = (tid & 7) ^ (trow & 7);
  const unsigned short* ag = A + (size_t)(bm + trow) * K_DIM + phys * 8;

  // --- B fragment row bases (global, per ni): row = bn+waveN+ni*16+l16,
  // lane K-chunk = quad*8 elems; kk selects +64 B via the offset imm;
  // K-tile advance = +64 elems (pointers bumped at end of each ITER).
  const unsigned short* bg0 = B + (size_t)(bn + waveN +  0 + l16) * K_DIM + quad * 8;
  const unsigned short* bg1 = B + (size_t)(bn + waveN + 16 + l16) * K_DIM + quad * 8;
  const unsigned short* bg2 = B + (size_t)(bn + waveN + 32 + l16) * K_DIM + quad * 8;
  const unsigned short* bg3 = B + (size_t)(bn + waveN + 48 + l16) * K_DIM + quad * 8;

  // --- A fragment LDS byte addresses (per kk; undo swizzle).
  const unsigned asb = (unsigned)(size_t)(AS3 void*)&As[0];
  unsigned a_addr[2];
#pragma unroll
  for (int kk = 0; kk < 2; ++kk) {
    const unsigned sw = (unsigned)((quad ^ (l16 & 7) ^ (kk * 4)) * 16);
    a_addr[kk] = asb + (unsigned)((waveM + l16) * BK * 2) + sw;
  }

  f32x4 acc[8][4] = {};
  s16x8 af0[4][2], af1[4][2];   // A m-half fragments
  s16x8 bU[2][2], bV[2][2];     // B n-half arrays (parity role-swap)

  // --- prologue: A(0) all rounds -> buf 0 (4 glds); n0(0) -> bU (4 glb).
  // VM_GATE(4) retires the 4 stage loads (oldest), leaves n0(0) in flight
  // -> steady-state entry (vm=4, lgkm=8 after af0 reads).
  STAGE_R(0, 0, 0);
  STAGE_R(0, 0, 1);
  STAGE_R(0, 0, 2);
  STAGE_R(0, 0, 3);
  GLB(bU[0][0], bg0, 0);  GLB(bU[0][1], bg0, 64);
  GLB(bU[1][0], bg1, 0);  GLB(bU[1][1], bg1, 64);
  SFENCE();
  VM_GATE(4);
  __builtin_amdgcn_s_barrier();
  SFENCE();
  RD_A(af0, 0, 0);   // af0(0) x8 -> lgkm ledger = 8
  SFENCE();

  for (int kt = 0; kt < NT; kt += 2) {
    ITER(kt, 0, bU, bV);
    ITER(kt + 1, 1, bV, bU);
  }

  // --- epilogue: C/D layout col=lane&15, row=quad*4+reg (unchanged order)
#pragma unroll
  for (int mi = 0; mi < 8; ++mi) {
#pragma unroll
    for (int ni = 0; ni < 4; ++ni) {
      const int o = bn + waveN + ni * 16 + l16;
#pragma unroll
      for (int r = 0; r < 4; ++r) {
        const int row = bm + waveM + mi * 16 + quad * 4 + r;
        C[(size_t)row * N_DIM + o] = acc[mi][ni][r];
      }
    }
  }
}

// ---------------------------------------------------------------------------
extern "C" void kernel_launch(void* const* d_in, const int* in_sizes, int n_in,
                              void* d_out, int out_size, void* d_ws, size_t ws_size,
                              hipStream_t stream) {
  const float* x        = (const float*)d_in[0];
  const int*   w_int    = (const int*)d_in[1];
  const float* w_scales = (const float*)d_in[2];
  const float* w_zeros  = (const float*)d_in[3];
  float* out = (float*)d_out;

  unsigned short* Aq = (unsigned short*)d_ws;                 // 8192*2048 bf16
  unsigned short* Wq = Aq + (size_t)M_DIM * K_DIM;            // 2048*2048 bf16

  const int prep_blocks = M_DIM + (N_DIM * (K_DIM / 8)) / 256;  // 8192 + 2048
  prep_kernel<<<prep_blocks, 256, 0, stream>>>(x, w_int, w_scales, w_zeros, Aq, Wq);
  dim3 grid(N_DIM / BN, M_DIM / BM);   // (8, 32) = 256 blocks = 1/CU
  gemm_kernel<<<grid, 512, 0, stream>>>(Aq, Wq, out);
}